// Round 1
// baseline (270.787 us; speedup 1.0000x reference)
//
#include <hip/hip_runtime.h>
#include <hip/hip_fp16.h>

// SoftNCutsLoss on MI355X — R14.
// batch: (4,1,32,32,32) f32, preds: (4,8,32,32,32) f32 -> out: (4,) f32
//
// R14 = R13 + three independent DS/VALU cuts (staging path byte-identical):
//  1. z-pair register blocking: each thread owns TWO w-adjacent voxels
//     (w, w+1). The union of the two lex-positive half-balls is 148 slots
//     covering 250 (voxel,offset) interactions -> each LDS neighbor load
//     (b32 + b128) is shared by up to 2 aff/fma blocks, and the 8x f16->f32
//     converts amortize across both voxels. DS ops in the accumulate loop:
//     124 -> 74 per thread (-40%); VALU -15%. Table split 4 ways round-robin
//     (37 entries/class <= 64-unroll limit, R12 lesson), class = tid>>7
//     (wave-uniform, no divergence).
//  2. LDS-transpose epilogue: vals[16] written per-thread (4x b128, row pad
//     20 floats for alignment + banks), then 16 groups x 32 readers column-
//     sum + width-32 shuffle. Replaces 96 ds_bpermute+add per thread (~3.7us
//     of DS issue per CU) with ~25 DS ops.
//  3. constexpr 343-entry S table indexed by per-axis border class (pos<3 ->
//     pos, pos>28 -> pos-25, else 3). Replaces the divergent 49x7 runtime
//     border loop (~1.5K VALU insts on half the waves of 100/128 tiles) with
//     2 cached rodata loads on class-0 threads.
// Math structure identical to R13 (pairwise symmetry, f16 neighbor preds,
// f32 own values, negative-lex pad S into sumw only).

#define EPS_F 2.220446049250313e-16f

constexpr int TD = 4, TH = 8, TW = 8;      // tile dims (d,h,w)
constexpr int HDh = 7, HHh = 14, HWh = 14; // halo: x forward-only +3, y/z +-3
constexpr int SYB = 17;                    // halo h-stride
constexpr int SXB = HHh * SYB;             // 238, halo d-stride
constexpr int NB  = 6 * SXB + 13 * SYB + 13 + 1;  // 1663 voxel slots
constexpr int NT = 512;                    // threads per block (8 waves)
constexpr int NBLK = 512;                  // 4 batches * 128 tiles
constexpr int NTASK = HDh * HHh * 4;       // 392 staging tasks (row x 4 chunks)

// exponent folding: aff = exp2(d2*K1 + c2*K2)
#define K1F (-0.014426950408889634f)       // -0.01 * log2(e)
#define K2F (-0.09016844005556021f)        // -log2(e)/16

// ---------- union table: offsets u rel voxel0; v0: u in H, v1: u-zhat in H ----------
// H = lex-positive half ball (x in 0..3; x==0 requires y>0 or (y==0,z>0)), c2<16.
// All offsets have positive linear index (x>=1 entries dominate; x==0 entries
// have y*SYB+z >= 1), so every ds_read folds the offset into its immediate.
struct UEnt { int off; bool v0; bool v1; float lw0; float lw1; };
struct UTab { UEnt e[64]; int n; };

constexpr bool inH(int x, int y, int z) {
    if (x < 0 || x > 3 || y < -3 || y > 3 || z < -3 || z > 3) return false;
    const int c2 = x * x + y * y + z * z;
    if (c2 == 0 || c2 >= 16) return false;
    if (x == 0 && (y < 0 || (y == 0 && z <= 0))) return false;
    return true;
}

constexpr UTab make_utab(int cls) {
    UTab t{}; t.n = 0; int idx = 0;
    for (int x = 0; x <= 3; ++x)
        for (int y = -3; y <= 3; ++y)
            for (int z = -3; z <= 4; ++z) {          // z to +4: H shifted by +zhat
                const bool v0 = inH(x, y, z);
                const bool v1 = inH(x, y, z - 1);
                if (!v0 && !v1) continue;
                const int my = idx & 3; ++idx;       // round-robin 4-way split
                if (my != cls) continue;
                t.e[t.n].off = x * SXB + y * SYB + z;
                t.e[t.n].v0 = v0; t.e[t.n].v1 = v1;
                t.e[t.n].lw0 = v0 ? (float)(x * x + y * y + z * z) * K2F : 0.f;
                t.e[t.n].lw1 = v1 ? (float)(x * x + y * y + (z - 1) * (z - 1)) * K2F : 0.f;
                ++t.n;                               // 37 per class (148 total)
            }
    return t;
}
constexpr UTab UT0 = make_utab(0);
constexpr UTab UT1 = make_utab(1);
constexpr UTab UT2 = make_utab(2);
constexpr UTab UT3 = make_utab(3);

// ---------- constexpr border-S table: S(class_d, class_h, class_w) ----------
// w(c2) = exp(-c2/16) for c2 in 0..15, exact-to-double literals.
constexpr float W16[16] = {
    1.0f,                    0.93941306281347578611f, 0.88249690258459546286f,
    0.82902911818040034301f, 0.77880078307140486825f, 0.73161562894664190813f,
    0.68728927879097219970f, 0.64565423513106973593f, 0.60653065971263342360f,
    0.56978282473092302544f, 0.53526142851899028012f, 0.50283157797094090696f,
    0.47236655274101470713f, 0.44374731008100323837f, 0.41686201967850837523f,
    0.39160740400665634335f };

struct STab { float s[343]; };
constexpr STab make_stab() {
    STab t{};
    for (int a = 0; a < 7; ++a)
        for (int b = 0; b < 7; ++b)
            for (int c = 0; c < 7; ++c) {
                const int pa = a < 3 ? a : (a == 3 ? 16 : a + 25);
                const int pb = b < 3 ? b : (b == 3 ? 16 : b + 25);
                const int pc = c < 3 ? c : (c == 3 ? 16 : c + 25);
                float s = 0.f;
                for (int dx = -3; dx <= 3; ++dx)
                    for (int dy = -3; dy <= 3; ++dy)
                        for (int dz = -3; dz <= 3; ++dz) {
                            const int c2 = dx * dx + dy * dy + dz * dz;
                            if (c2 >= 16) continue;
                            const bool neg = (dx < 0) ||
                                (dx == 0 && (dy < 0 || (dy == 0 && dz < 0)));
                            if (!neg) continue;
                            const bool in = (pa + dx) >= 0 && (pa + dx) < 32 &&
                                            (pb + dy) >= 0 && (pb + dy) < 32 &&
                                            (pc + dz) >= 0 && (pc + dz) < 32;
                            if (!in) s += W16[c2];
                        }
                t.s[(a * 7 + b) * 7 + c] = s;
            }
    return t;
}
__constant__ STab STAB = make_stab();

__device__ __forceinline__ int bcls(int p) {
    return p < 3 ? p : (p > 28 ? p - 25 : 3);
}

__device__ __forceinline__ unsigned pack2(float a, float b) {
    return (unsigned)__half_as_ushort(__float2half(a)) |
           ((unsigned)__half_as_ushort(__float2half(b)) << 16);
}

template <int CLS>
__device__ __forceinline__ void accum_union(const float* __restrict__ sB,
                                            const uint4* __restrict__ sPk,
                                            int vown, float b0, float b1,
                                            float a0[9], float a1[9]) {
    constexpr UTab T = CLS == 0 ? UT0 : CLS == 1 ? UT1 : CLS == 2 ? UT2 : UT3;
    constexpr int N = T.n;
    constexpr int N4 = (N / 4) * 4;

#pragma unroll
    for (int i = 0; i < N4; i += 4) {
        float sbv[4];
        uint4 pkv[4];
#pragma unroll
        for (int j = 0; j < 4; ++j) {
            const int nv = vown + T.e[i + j].off;
            sbv[j] = sB[nv];
            pkv[j] = sPk[nv];
        }
#pragma unroll
        for (int j = 0; j < 4; ++j) {
            __half2 h[4];
            __builtin_memcpy(h, &pkv[j], 16);
            float pf[8];
            pf[0] = __half2float(__low2half(h[0]));  pf[1] = __half2float(__high2half(h[0]));
            pf[2] = __half2float(__low2half(h[1]));  pf[3] = __half2float(__high2half(h[1]));
            pf[4] = __half2float(__low2half(h[2]));  pf[5] = __half2float(__high2half(h[2]));
            pf[6] = __half2float(__low2half(h[3]));  pf[7] = __half2float(__high2half(h[3]));
            if (T.e[i + j].v0) {                      // folds at compile time
                const float d = b0 - sbv[j];
                const float aff =
                    __builtin_amdgcn_exp2f(__builtin_fmaf(d * d, K1F, T.e[i + j].lw0));
                a0[8] += aff;
#pragma unroll
                for (int k = 0; k < 8; ++k) a0[k] = __builtin_fmaf(aff, pf[k], a0[k]);
            }
            if (T.e[i + j].v1) {
                const float d = b1 - sbv[j];
                const float aff =
                    __builtin_amdgcn_exp2f(__builtin_fmaf(d * d, K1F, T.e[i + j].lw1));
                a1[8] += aff;
#pragma unroll
                for (int k = 0; k < 8; ++k) a1[k] = __builtin_fmaf(aff, pf[k], a1[k]);
            }
        }
    }
#pragma unroll
    for (int i = N4; i < N; ++i) {                    // remainder (<=3)
        const int nv = vown + T.e[i].off;
        const float sb = sB[nv];
        const uint4 pk = sPk[nv];
        __half2 h[4];
        __builtin_memcpy(h, &pk, 16);
        float pf[8];
        pf[0] = __half2float(__low2half(h[0]));  pf[1] = __half2float(__high2half(h[0]));
        pf[2] = __half2float(__low2half(h[1]));  pf[3] = __half2float(__high2half(h[1]));
        pf[4] = __half2float(__low2half(h[2]));  pf[5] = __half2float(__high2half(h[2]));
        pf[6] = __half2float(__low2half(h[3]));  pf[7] = __half2float(__high2half(h[3]));
        if (T.e[i].v0) {
            const float d = b0 - sb;
            const float aff =
                __builtin_amdgcn_exp2f(__builtin_fmaf(d * d, K1F, T.e[i].lw0));
            a0[8] += aff;
#pragma unroll
            for (int k = 0; k < 8; ++k) a0[k] = __builtin_fmaf(aff, pf[k], a0[k]);
        }
        if (T.e[i].v1) {
            const float d = b1 - sb;
            const float aff =
                __builtin_amdgcn_exp2f(__builtin_fmaf(d * d, K1F, T.e[i].lw1));
            a1[8] += aff;
#pragma unroll
            for (int k = 0; k < 8; ++k) a1[k] = __builtin_fmaf(aff, pf[k], a1[k]);
        }
    }
}

__global__ __launch_bounds__(NT, 4)
void softncuts_main(const float* __restrict__ batch,
                    const float* __restrict__ preds,
                    float* __restrict__ partials) {
    __shared__ float sB[NB];            // batch halo, f32 (6.5 KB)
    __shared__ uint4 sPk[NB];           // preds halo, 8 x f16 packed (26 KB)
    __shared__ float valsT[NT * 20];    // epilogue transpose, row pad 20 (40 KB)

    const int bid  = blockIdx.x;
    const int bb   = bid >> 7;          // batch index 0..3
    const int tile = bid & 127;
    const int tw = tile & 3;            // -> w0 = tw*8
    const int th = (tile >> 2) & 3;     // -> h0 = th*8
    const int td = tile >> 4;           // -> d0 = td*4
    const int d0 = td * TD, h0 = th * TH, w0 = tw * TW;

    const int tid  = threadIdx.x;

    const float* bbase = batch + (size_t)bb * 32768;
    const float* pbase = preds + (size_t)bb * 8 * 32768;

    // ---- stage forward-x halo, float4-vectorized along w (unchanged from R13) ----
    if (tid < NTASK) {
        const int t   = tid;
        const int c   = t & 3;
        const int row = t >> 2;
        const int hh  = row % HHh;
        const int hd  = row / HHh;
        const int gd  = d0 + hd;
        const int gh  = h0 + hh - 3;
        const int gw0 = w0 - 4 + c * 4;
        const int hwb = c * 4 - 1;
        const bool fast = (gd < 32) & ((unsigned)gh < 32u) & (gw0 >= 0) & (gw0 + 3 < 32);
        if (fast) {
            const int sidx = (gd * 32 + gh) * 32 + gw0;   // 16B-aligned
            float4 pv[9];
            pv[0] = *(const float4*)(bbase + sidx);
#pragma unroll
            for (int k = 0; k < 8; ++k)
                pv[k + 1] = *(const float4*)(pbase + sidx + k * 32768);
#pragma unroll
            for (int e = 0; e < 4; ++e) {
                const int hw = hwb + e;
                if (hw < 0 || hw >= HWh) continue;
                const int f = hd * SXB + hh * SYB + hw;
                sB[f] = ((const float*)&pv[0])[e];
                unsigned u[4];
#pragma unroll
                for (int k = 0; k < 4; ++k)
                    u[k] = pack2(((const float*)&pv[2 * k + 1])[e],
                                 ((const float*)&pv[2 * k + 2])[e]);
                sPk[f] = make_uint4(u[0], u[1], u[2], u[3]);
            }
        } else {
#pragma unroll
            for (int e = 0; e < 4; ++e) {
                const int hw = hwb + e;
                if (hw < 0 || hw >= HWh) continue;
                const int gw = gw0 + e;
                const bool in = (gd < 32) & ((unsigned)gh < 32u) & ((unsigned)gw < 32u);
                const int sidx = (gd * 32 + gh) * 32 + gw;
                const int f = hd * SXB + hh * SYB + hw;
                sB[f] = in ? bbase[sidx] : EPS_F;
                unsigned u[4];
#pragma unroll
                for (int k = 0; k < 4; ++k)
                    u[k] = pack2(in ? pbase[sidx + (2 * k) * 32768]     : 0.f,
                                 in ? pbase[sidx + (2 * k + 1) * 32768] : 0.f);
                sPk[f] = make_uint4(u[0], u[1], u[2], u[3]);
            }
        }
    }
    __syncthreads();

    // ---- thread -> (voxel pair, table class) ----
    const int cid  = tid >> 7;          // 0..3, wave-uniform (2 waves per class)
    const int vtid = tid & 127;         // pair id: 4 (w-pairs) x 8 (h) x 4 (d)
    const int lwp = vtid & 3;           // own w = {lwp*2, lwp*2+1}
    const int lh  = (vtid >> 2) & 7;
    const int ld  = vtid >> 5;

    // ---- own voxel values from GLOBAL f32 (float2: both pair members) ----
    const int gdo = d0 + ld, gho = h0 + lh, gw0v = w0 + lwp * 2;
    const int sidx0 = (gdo * 32 + gho) * 32 + gw0v;   // even -> float2 aligned
    const float2 bv = *(const float2*)(bbase + sidx0);
    const float b0 = bv.x, b1 = bv.y;
    float q0[8], q1[8];
#pragma unroll
    for (int k = 0; k < 8; ++k) {
        const float2 qv = *(const float2*)(pbase + sidx0 + k * 32768);
        q0[k] = qv.x; q1[k] = qv.y;
    }

    const int vown = ld * SXB + (lh + 3) * SYB + (lwp * 2 + 3);

    float a0[9], a1[9];
#pragma unroll
    for (int i = 0; i < 9; ++i) { a0[i] = 0.f; a1[i] = 0.f; }

    switch (cid) {
        case 0:  accum_union<0>(sB, sPk, vown, b0, b1, a0, a1); break;
        case 1:  accum_union<1>(sB, sPk, vown, b0, b1, a0, a1); break;
        case 2:  accum_union<2>(sB, sPk, vown, b0, b1, a0, a1); break;
        default: accum_union<3>(sB, sPk, vown, b0, b1, a0, a1); break;
    }

    // ---- self + pad terms, exactly once per voxel (class 0 threads) ----
    float sp0 = 0.f, sp1 = 0.f;
    if (cid == 0) {
        const int base = (bcls(gdo) * 7 + bcls(gho)) * 7;
        const float S0 = STAB.s[base + bcls(gw0v)];
        const float S1 = STAB.s[base + bcls(gw0v + 1)];
        const float db0 = b0 - EPS_F, db1 = b1 - EPS_F;
        sp0 = 1.f + S0 * __expf(db0 * db0 * -0.01f);
        sp1 = 1.f + S1 * __expf(db1 * db1 * -0.01f);
    }

    float vals[16];
#pragma unroll
    for (int k = 0; k < 8; ++k) {
        const float s0 = (cid == 0) ? q0[k] : 0.f;
        const float s1 = (cid == 0) ? q1[k] : 0.f;
        vals[k]     = q0[k] * (2.f * a0[k] + s0) + q1[k] * (2.f * a1[k] + s1);
        vals[8 + k] = q0[k] * (a0[8] + sp0) + a0[k]
                    + q1[k] * (a1[8] + sp1) + a1[k];
    }

    // ---- LDS-transpose block reduction (replaces 96 bpermutes/thread) ----
    {
        float* vr = &valsT[tid * 20];                 // 80 B rows, 16B aligned
        ((float4*)vr)[0] = make_float4(vals[0],  vals[1],  vals[2],  vals[3]);
        ((float4*)vr)[1] = make_float4(vals[4],  vals[5],  vals[6],  vals[7]);
        ((float4*)vr)[2] = make_float4(vals[8],  vals[9],  vals[10], vals[11]);
        ((float4*)vr)[3] = make_float4(vals[12], vals[13], vals[14], vals[15]);
    }
    __syncthreads();
    {
        const int val = tid >> 5;                     // 0..15
        const int r   = tid & 31;                     // 0..31 readers per value
        float s = 0.f;
#pragma unroll
        for (int k = 0; k < 16; ++k)
            s += valsT[(r + 32 * k) * 20 + val];
        for (int off = 16; off; off >>= 1) s += __shfl_down(s, off, 32);
        if (r == 0) partials[val * NBLK + bid] = s;
    }
}

__global__ __launch_bounds__(1024)
void softncuts_finalize(const float* __restrict__ partials,
                        float* __restrict__ out) {
    __shared__ float red[64];
    const int tid = threadIdx.x;          // 0..1023
    const int group = tid >> 4;           // 0..63 = bb*16 + slot
    const int j0 = tid & 15;
    const int slot = group & 15;
    const int bb = group >> 4;

    const float* p = partials + slot * NBLK + bb * 128;   // 128 tiles per batch
    float s = 0.f;
#pragma unroll
    for (int k = 0; k < 8; ++k) s += p[j0 + 16 * k];
    for (int off = 8; off; off >>= 1) s += __shfl_down(s, off, 16);
    if (j0 == 0) red[group] = s;
    __syncthreads();

    if (tid < 4) {
        float accv = 0.f;
#pragma unroll
        for (int k = 0; k < 8; ++k)
            accv += red[tid * 16 + k] / red[tid * 16 + 8 + k];
        out[tid] = 8.0f - accv;
    }
}

extern "C" void kernel_launch(void* const* d_in, const int* in_sizes, int n_in,
                              void* d_out, int out_size, void* d_ws, size_t ws_size,
                              hipStream_t stream) {
    const float* batch = (const float*)d_in[0];
    const float* preds = (const float*)d_in[1];
    float* out      = (float*)d_out;
    float* partials = (float*)d_ws;   // 16*NBLK floats = 32 KB

    softncuts_main<<<dim3(NBLK), dim3(NT), 0, stream>>>(batch, preds, partials);
    softncuts_finalize<<<dim3(1), dim3(1024), 0, stream>>>(partials, out);
}

// Round 2
// 78.482 us; speedup vs baseline: 3.4503x; 3.4503x over previous
//
#include <hip/hip_runtime.h>
#include <hip/hip_fp16.h>

// SoftNCutsLoss on MI355X — R15.
// batch: (4,1,32,32,32) f32, preds: (4,8,32,32,32) f32 -> out: (4,) f32
//
// R15 = R13's proven accumulate loop + two safe riders from R14.
// R14 post-mortem (counters): pair-blocked union table (37 entries x ~2x body)
// exceeded LLVM's full-unroll budget -> loop stayed rolled -> 20B/entry table
// materialized per-thread in SCRATCH (FETCH 300MB, WRITE 293MB, VGPR 64,
// VALUBusy 4.3%, 215us). Lesson: unroll budget = entries x body size, not
// entries alone. Reverted to R13's accum_pairs (62/63 single-voxel entries,
// proven to fold offsets into ds_read immediates).
// Riders kept (neither touches the accumulate loop):
//  1. LDS-transpose epilogue: vals[16] written per-thread (4x ds_write_b128,
//     row stride 20 dwords = conflict-free), 16 groups x 32 readers column-sum
//     + width-32 shuffle. Replaces 96 ds_bpermute+add per thread.
//  2. constexpr 343-entry S table in __constant__, indexed by per-axis border
//     class (p<3 -> p, p>28 -> p-25, else 3). Replaces the divergent 49x7
//     runtime border loop; 'border' branch deleted.
// Math identical to R13 (pairwise symmetry + negative-lex pad S, absmax 0.0).

#define EPS_F 2.220446049250313e-16f

constexpr int TD = 4, TH = 8, TW = 8;      // tile dims (d,h,w)
constexpr int HDh = 7, HHh = 14, HWh = 14; // halo: x forward-only +3, y/z +-3
constexpr int SYB = 17;                    // halo h-stride
constexpr int SXB = HHh * SYB;             // 238, halo d-stride
constexpr int NB  = 6 * SXB + 13 * SYB + 13 + 1;  // 1663 voxel slots
constexpr int NT = 512;                    // threads per block (8 waves)
constexpr int NBLK = 512;                  // 4 batches * 128 tiles
constexpr int NTASK = HDh * HHh * 4;       // 392 staging tasks (row x 4 chunks)

// exponent folding: aff = exp2(d2*K1 + c2*K2)
#define K1F (-0.014426950408889634f)       // -0.01 * log2(e)
#define K2F (-0.09016844005556021f)        // -log2(e)/16

struct Ent { int off; float lw; };
struct Tab { Ent e[64]; int n; };

constexpr Tab make_tab(int half) {
    Tab t{};
    t.n = 0;
    for (int dxq = 0; dxq < 4; ++dxq)
        for (int dyi = 0; dyi < 7; ++dyi)
            for (int dzi = 0; dzi < 7; ++dzi) {
                int dy = dyi - 3, dz = dzi - 3;
                if (dxq == 0) {                  // lexicographic positivity
                    if (dy < 0) continue;
                    if (dy == 0 && dz <= 0) continue;
                }
                int c2 = dxq * dxq + dy * dy + dz * dz;
                if (c2 >= 16) continue;          // ball cutoff
                if (((dyi + dzi) & 1) != half) continue;
                t.e[t.n].off = dxq * SXB + dy * SYB + dz;
                t.e[t.n].lw  = (float)c2 * K2F;
                ++t.n;                           // 62 / 63
            }
    return t;
}
constexpr Tab TAB0 = make_tab(0);
constexpr Tab TAB1 = make_tab(1);

// ---------- constexpr border-S table: S(class_d, class_h, class_w) ----------
// w(c2) = exp(-c2/16) for c2 in 0..15, exact-to-double literals.
constexpr float W16[16] = {
    1.0f,                    0.93941306281347578611f, 0.88249690258459546286f,
    0.82902911818040034301f, 0.77880078307140486825f, 0.73161562894664190813f,
    0.68728927879097219970f, 0.64565423513106973593f, 0.60653065971263342360f,
    0.56978282473092302544f, 0.53526142851899028012f, 0.50283157797094090696f,
    0.47236655274101470713f, 0.44374731008100323837f, 0.41686201967850837523f,
    0.39160740400665634335f };

struct STab { float s[343]; };
constexpr STab make_stab() {
    STab t{};
    for (int a = 0; a < 7; ++a)
        for (int b = 0; b < 7; ++b)
            for (int c = 0; c < 7; ++c) {
                const int pa = a < 3 ? a : (a == 3 ? 16 : a + 25);
                const int pb = b < 3 ? b : (b == 3 ? 16 : b + 25);
                const int pc = c < 3 ? c : (c == 3 ? 16 : c + 25);
                float s = 0.f;
                for (int dx = -3; dx <= 3; ++dx)
                    for (int dy = -3; dy <= 3; ++dy)
                        for (int dz = -3; dz <= 3; ++dz) {
                            const int c2 = dx * dx + dy * dy + dz * dz;
                            if (c2 >= 16) continue;
                            const bool neg = (dx < 0) ||
                                (dx == 0 && (dy < 0 || (dy == 0 && dz < 0)));
                            if (!neg) continue;
                            const bool in = (pa + dx) >= 0 && (pa + dx) < 32 &&
                                            (pb + dy) >= 0 && (pb + dy) < 32 &&
                                            (pc + dz) >= 0 && (pc + dz) < 32;
                            if (!in) s += W16[c2];
                        }
                t.s[(a * 7 + b) * 7 + c] = s;
            }
    return t;
}
__constant__ STab STAB = make_stab();

__device__ __forceinline__ int bcls(int p) {
    return p < 3 ? p : (p > 28 ? p - 25 : 3);
}

__device__ __forceinline__ unsigned pack2(float a, float b) {
    return (unsigned)__half_as_ushort(__float2half(a)) |
           ((unsigned)__half_as_ushort(__float2half(b)) << 16);
}

template <int HALF>
__device__ __forceinline__ void accum_pairs(const float* __restrict__ sB,
                                            const uint4* __restrict__ sPk,
                                            int vown, float b_own,
                                            float acc[9]) {
    constexpr Tab T = HALF ? TAB1 : TAB0;
    constexpr int N = HALF ? TAB1.n : TAB0.n;
    constexpr int N4 = (N / 4) * 4;

#pragma unroll
    for (int i = 0; i < N4; i += 4) {
        float sb[4];
        uint4 pk[4];
#pragma unroll
        for (int j = 0; j < 4; ++j) {
            const int nv = vown + T.e[i + j].off;
            sb[j] = sB[nv];
            pk[j] = sPk[nv];
        }
#pragma unroll
        for (int j = 0; j < 4; ++j) {
            const float d = b_own - sb[j];
            const float aff =
                __builtin_amdgcn_exp2f(__builtin_fmaf(d * d, K1F, T.e[i + j].lw));
            acc[8] += aff;
            __half2 h[4];
            __builtin_memcpy(h, &pk[j], 16);
            acc[0] = __builtin_fmaf(aff, __half2float(__low2half(h[0])),  acc[0]);
            acc[1] = __builtin_fmaf(aff, __half2float(__high2half(h[0])), acc[1]);
            acc[2] = __builtin_fmaf(aff, __half2float(__low2half(h[1])),  acc[2]);
            acc[3] = __builtin_fmaf(aff, __half2float(__high2half(h[1])), acc[3]);
            acc[4] = __builtin_fmaf(aff, __half2float(__low2half(h[2])),  acc[4]);
            acc[5] = __builtin_fmaf(aff, __half2float(__high2half(h[2])), acc[5]);
            acc[6] = __builtin_fmaf(aff, __half2float(__low2half(h[3])),  acc[6]);
            acc[7] = __builtin_fmaf(aff, __half2float(__high2half(h[3])), acc[7]);
        }
    }
#pragma unroll
    for (int i = N4; i < N; ++i) {               // remainder (<=3)
        const int nv = vown + T.e[i].off;
        const float sb = sB[nv];
        const uint4 pk = sPk[nv];
        const float d = b_own - sb;
        const float aff =
            __builtin_amdgcn_exp2f(__builtin_fmaf(d * d, K1F, T.e[i].lw));
        acc[8] += aff;
        __half2 h[4];
        __builtin_memcpy(h, &pk, 16);
        acc[0] = __builtin_fmaf(aff, __half2float(__low2half(h[0])),  acc[0]);
        acc[1] = __builtin_fmaf(aff, __half2float(__high2half(h[0])), acc[1]);
        acc[2] = __builtin_fmaf(aff, __half2float(__low2half(h[1])),  acc[2]);
        acc[3] = __builtin_fmaf(aff, __half2float(__high2half(h[1])), acc[3]);
        acc[4] = __builtin_fmaf(aff, __half2float(__low2half(h[2])),  acc[4]);
        acc[5] = __builtin_fmaf(aff, __half2float(__high2half(h[2])), acc[5]);
        acc[6] = __builtin_fmaf(aff, __half2float(__low2half(h[3])),  acc[6]);
        acc[7] = __builtin_fmaf(aff, __half2float(__high2half(h[3])), acc[7]);
    }
}

__global__ __launch_bounds__(NT, 4)
void softncuts_main(const float* __restrict__ batch,
                    const float* __restrict__ preds,
                    float* __restrict__ partials) {
    __shared__ float sB[NB];            // batch halo, f32 (6.5 KB)
    __shared__ uint4 sPk[NB];           // preds halo, 8 x f16 packed (26 KB)
    __shared__ float valsT[NT * 20];    // epilogue transpose, row stride 20 (40 KB)

    const int bid  = blockIdx.x;
    const int bb   = bid >> 7;          // batch index 0..3
    const int tile = bid & 127;
    const int tw = tile & 3;            // -> w0 = tw*8
    const int th = (tile >> 2) & 3;     // -> h0 = th*8
    const int td = tile >> 4;           // -> d0 = td*4
    const int d0 = td * TD, h0 = th * TH, w0 = tw * TW;

    const int tid  = threadIdx.x;
    const int half = tid >> 8;          // 0/1, wave-uniform (waves 0-3 vs 4-7)
    const int vtid = tid & 255;
    const int lw = vtid & 7;            // 0..7
    const int lh = (vtid >> 3) & 7;     // 0..7
    const int ld = vtid >> 6;           // 0..3

    const float* bbase = batch + (size_t)bb * 32768;
    const float* pbase = preds + (size_t)bb * 8 * 32768;

    // ---- stage forward-x halo, float4-vectorized along w ----
    // chunk grid aligned to gw % 4 == 0: chunks start at w0-4+4c, hw = 4c-1+e.
    if (tid < NTASK) {
        const int t   = tid;
        const int c   = t & 3;
        const int row = t >> 2;
        const int hh  = row % HHh;
        const int hd  = row / HHh;
        const int gd  = d0 + hd;
        const int gh  = h0 + hh - 3;
        const int gw0 = w0 - 4 + c * 4;
        const int hwb = c * 4 - 1;
        const bool fast = (gd < 32) & ((unsigned)gh < 32u) & (gw0 >= 0) & (gw0 + 3 < 32);
        if (fast) {
            const int sidx = (gd * 32 + gh) * 32 + gw0;   // 16B-aligned
            float4 pv[9];
            pv[0] = *(const float4*)(bbase + sidx);
#pragma unroll
            for (int k = 0; k < 8; ++k)
                pv[k + 1] = *(const float4*)(pbase + sidx + k * 32768);
#pragma unroll
            for (int e = 0; e < 4; ++e) {
                const int hw = hwb + e;
                if (hw < 0 || hw >= HWh) continue;
                const int f = hd * SXB + hh * SYB + hw;
                sB[f] = ((const float*)&pv[0])[e];
                unsigned u[4];
#pragma unroll
                for (int k = 0; k < 4; ++k)
                    u[k] = pack2(((const float*)&pv[2 * k + 1])[e],
                                 ((const float*)&pv[2 * k + 2])[e]);
                sPk[f] = make_uint4(u[0], u[1], u[2], u[3]);
            }
        } else {
#pragma unroll
            for (int e = 0; e < 4; ++e) {
                const int hw = hwb + e;
                if (hw < 0 || hw >= HWh) continue;
                const int gw = gw0 + e;
                const bool in = (gd < 32) & ((unsigned)gh < 32u) & ((unsigned)gw < 32u);
                const int sidx = (gd * 32 + gh) * 32 + gw;
                const int f = hd * SXB + hh * SYB + hw;
                sB[f] = in ? bbase[sidx] : EPS_F;
                unsigned u[4];
#pragma unroll
                for (int k = 0; k < 4; ++k)
                    u[k] = pack2(in ? pbase[sidx + (2 * k) * 32768]     : 0.f,
                                 in ? pbase[sidx + (2 * k + 1) * 32768] : 0.f);
                sPk[f] = make_uint4(u[0], u[1], u[2], u[3]);
            }
        }
    }
    __syncthreads();

    // ---- own voxel values from GLOBAL f32 (full precision for b_own and q) ----
    const int gdo = d0 + ld, gho = h0 + lh, gwo = w0 + lw;
    const int sidx_own = (gdo * 32 + gho) * 32 + gwo;
    const float b_own = bbase[sidx_own];
    float q[8];
#pragma unroll
    for (int k = 0; k < 8; ++k) q[k] = pbase[sidx_own + k * 32768];

    const int vown = ld * SXB + (lh + 3) * SYB + (lw + 3);

    float acc[9];
#pragma unroll
    for (int i = 0; i < 9; ++i) acc[i] = 0.f;

    if (half == 0) accum_pairs<0>(sB, sPk, vown, b_own, acc);
    else           accum_pairs<1>(sB, sPk, vown, b_own, acc);

    // ---- self + pad terms (table lookup, half==0 threads only) ----
    float selfpad = 0.f;
    if (half == 0) {
        const float S = STAB.s[(bcls(gdo) * 7 + bcls(gho)) * 7 + bcls(gwo)];
        const float db = b_own - EPS_F;
        selfpad = 1.f + S * __expf(db * db * -0.01f);
    }

    // ---- per-lane contributions (voxel shared by 2 threads; self terms once) ----
    float vals[16];
#pragma unroll
    for (int k = 0; k < 8; ++k) {
        vals[k]     = q[k] * (2.f * acc[k] + ((half == 0) ? q[k] : 0.f));
        vals[8 + k] = q[k] * (acc[8] + selfpad) + acc[k];
    }

    // ---- LDS-transpose block reduction (replaces 96 bpermutes/thread) ----
    {
        float* vr = &valsT[tid * 20];                 // 80 B rows, 16B aligned
        ((float4*)vr)[0] = make_float4(vals[0],  vals[1],  vals[2],  vals[3]);
        ((float4*)vr)[1] = make_float4(vals[4],  vals[5],  vals[6],  vals[7]);
        ((float4*)vr)[2] = make_float4(vals[8],  vals[9],  vals[10], vals[11]);
        ((float4*)vr)[3] = make_float4(vals[12], vals[13], vals[14], vals[15]);
    }
    __syncthreads();
    {
        const int val = tid >> 5;                     // 0..15
        const int r   = tid & 31;                     // 32 readers per value
        float s = 0.f;
#pragma unroll
        for (int k = 0; k < 16; ++k)
            s += valsT[(r + 32 * k) * 20 + val];
        for (int off = 16; off; off >>= 1) s += __shfl_down(s, off, 32);
        if (r == 0) partials[val * NBLK + bid] = s;
    }
}

__global__ __launch_bounds__(1024)
void softncuts_finalize(const float* __restrict__ partials,
                        float* __restrict__ out) {
    __shared__ float red[64];
    const int tid = threadIdx.x;          // 0..1023
    const int group = tid >> 4;           // 0..63 = bb*16 + slot
    const int j0 = tid & 15;
    const int slot = group & 15;
    const int bb = group >> 4;

    const float* p = partials + slot * NBLK + bb * 128;   // 128 tiles per batch
    float s = 0.f;
#pragma unroll
    for (int k = 0; k < 8; ++k) s += p[j0 + 16 * k];
    for (int off = 8; off; off >>= 1) s += __shfl_down(s, off, 16);
    if (j0 == 0) red[group] = s;
    __syncthreads();

    if (tid < 4) {
        float accv = 0.f;
#pragma unroll
        for (int k = 0; k < 8; ++k)
            accv += red[tid * 16 + k] / red[tid * 16 + 8 + k];
        out[tid] = 8.0f - accv;
    }
}

extern "C" void kernel_launch(void* const* d_in, const int* in_sizes, int n_in,
                              void* d_out, int out_size, void* d_ws, size_t ws_size,
                              hipStream_t stream) {
    const float* batch = (const float*)d_in[0];
    const float* preds = (const float*)d_in[1];
    float* out      = (float*)d_out;
    float* partials = (float*)d_ws;   // 16*NBLK floats = 32 KB

    softncuts_main<<<dim3(NBLK), dim3(NT), 0, stream>>>(batch, preds, partials);
    softncuts_finalize<<<dim3(1), dim3(1024), 0, stream>>>(partials, out);
}